// Round 5
// baseline (581.772 us; speedup 1.0000x reference)
//
#include <hip/hip_runtime.h>
#include <hip/hip_bf16.h>
#include <stdint.h>

typedef short short8 __attribute__((ext_vector_type(8)));
typedef float f32x4 __attribute__((ext_vector_type(4)));
typedef float float4v __attribute__((ext_vector_type(4)));

#define KDIM 4096
#define TDIM 11008
#define BDIM 4096

static __device__ __forceinline__ unsigned short f2bf(float f) {
  unsigned u = __builtin_bit_cast(unsigned, f);
  u += 0x7FFFu + ((u >> 16) & 1u);
  return (unsigned short)(u >> 16);
}

// ---------------- kernel 1: dequant int4 -> bf16, transposed Wt[T][K] ----------------
__global__ __launch_bounds__(256) void dequant_k(const unsigned* __restrict__ qw,
                                                 const float* __restrict__ scales,
                                                 const float* __restrict__ zeros,
                                                 unsigned short* __restrict__ wt) {
  int idx = blockIdx.x * 256 + threadIdx.x;
  int rb = idx / TDIM;
  int t = idx - rb * TDIM;
  int r0 = rb * 4;
  int g = rb >> 2;
  float s = scales[(size_t)g * TDIM + t];
  float z = zeros[(size_t)g * TDIM + t];
  float nzs = -z * s;
#pragma unroll
  for (int c = 0; c < 4; ++c) {
    unsigned q = qw[(size_t)(r0 + c) * TDIM + t];
    short8 o;
#pragma unroll
    for (int i = 0; i < 8; ++i) {
      float w = fmaf((float)((q >> (4 * i)) & 0xFu), s, nzs);
      o[i] = (short)f2bf(w);
    }
    *(short8*)(wt + (size_t)t * KDIM + (r0 + c) * 8) = o;
  }
}

// ---------------- kernel 2: x f32 -> bf16 ----------------
__global__ __launch_bounds__(256) void cvtx_k(const float* __restrict__ x,
                                              unsigned short* __restrict__ xb) {
  size_t i = ((size_t)blockIdx.x * 256 + threadIdx.x) * 8;
  float4v a = *(const float4v*)(x + i);
  float4v b = *(const float4v*)(x + i + 4);
  short8 o;
  o[0] = (short)f2bf(a[0]); o[1] = (short)f2bf(a[1]);
  o[2] = (short)f2bf(a[2]); o[3] = (short)f2bf(a[3]);
  o[4] = (short)f2bf(b[0]); o[5] = (short)f2bf(b[1]);
  o[6] = (short)f2bf(b[2]); o[7] = (short)f2bf(b[3]);
  *(short8*)(xb + i) = o;
}

// ---------------- kernel 3: 256x256 bf16 GEMM, 1-phase-lookahead register pipeline ----
// Per tile (K=64), 4 phases, ONE barrier each. Phase p issues ds_reads for phase p+1's
// fragments; MFMA(p) consumes regs loaded at p-1 (compiler emits counted lgkmcnt for
// the register deps, leaving lookahead reads in flight under the MFMA cluster).
// Staging slots (set staged at q lands after vmcnt @ end q+2, earliest read q+3):
//   ph0: A0(T+1)   [read @ph3(T)   -> land by end ph2(T): vmcnt(6)@ph2 retires it]
//   ph1: B0+B1(T+1)[read @ph0(T+1) -> land by end ph3(T): vmcnt(2)@ph3 retires it]
//   ph2: A1(T+1)   [read @ph1(T+1) -> land by end ph0(T+1): vmcnt(2)@ph0 retires it]
// Outstanding never drained to 0 in the loop.
static __device__ __forceinline__ void gload16(const void* g, void* l) {
  __builtin_amdgcn_global_load_lds(
      (const __attribute__((address_space(1))) unsigned*)g,
      (__attribute__((address_space(3))) unsigned*)l, 16, 0, 0);
}

#define PH_BAR() asm volatile("s_barrier" ::: "memory")
#define VMC(N) asm volatile("s_waitcnt vmcnt(" #N ")" ::: "memory")

__global__ __launch_bounds__(512, 2) void gemm5_k(const unsigned short* __restrict__ xb,
                                                  const unsigned short* __restrict__ wt,
                                                  const float* __restrict__ bias,
                                                  float* __restrict__ out) {
  __shared__ unsigned short sA[2 * 256 * 64];  // 64 KiB [buf][row][64K], 128B rows, XOR swz
  __shared__ unsigned short sB[2 * 256 * 64];  // 64 KiB
  const int tid = threadIdx.x;
  const int lane = tid & 63;
  const int wid = tid >> 6;
  const int wm = wid >> 2, wn = wid & 3;

  // XCD swizzle: nwg = 16*43 = 688 = 8*86
  const int bid = blockIdx.x;
  const int swz = (bid & 7) * 86 + (bid >> 3);
  const int mb = swz / 43, nb = swz % 43;
  const int m0 = mb * 256, n0 = nb * 256;

  char* sAc = (char*)sA;
  char* sBc = (char*)sB;

  // staging precompute (3-bit XOR both-sides swizzle, R3/R4-verified conflict-free)
  const int sr = tid >> 3;
  const int pcb = (tid & 7) * 16;
  const int kbel = ((tid & 7) ^ (sr & 7)) * 8;
  const int grB = (sr >> 5) * 64 + (sr & 31);
  const unsigned short* srcA = xb + (size_t)m0 * KDIM + kbel;
  const unsigned short* srcB = wt + (size_t)n0 * KDIM + kbel;

  auto stage2 = [&](const unsigned short* src, char* dst, int gr, int koff) {
    gload16(src + (size_t)gr * KDIM + koff, dst + gr * 128);
    gload16(src + (size_t)(gr + 128) * KDIM + koff, dst + (gr + 128) * 128);
  };
  auto stA = [&](int b, int QM, int kt) { stage2(srcA, sAc + b * 32768 + pcb, QM * 64 + sr, kt * 64); };
  auto stB = [&](int b, int QN, int kt) { stage2(srcB, sBc + b * 32768 + pcb, QN * 32 + grB, kt * 64); };

  // read addressing: phys chunk = (ks*4+hi) ^ (r15&7)
  const int r15 = lane & 15;
  const int hi = lane >> 4;
  const int sw0 = ((hi) ^ (r15 & 7)) * 16;
  const int sw1 = ((4 + hi) ^ (r15 & 7)) * 16;
  const char* aR0 = sAc + (wm * 128 + r15) * 128;
  const char* aR1 = sAc + 32768 + (wm * 128 + r15) * 128;
  const char* bR0 = sBc + (wn * 64 + r15) * 128;
  const char* bR1 = sBc + 32768 + (wn * 64 + r15) * 128;

  f32x4 acc[8][4];
#pragma unroll
  for (int i = 0; i < 8; ++i)
#pragma unroll
    for (int j = 0; j < 4; ++j) acc[i][j] = (f32x4){0.f, 0.f, 0.f, 0.f};

  short8 av0[4][2], av1[4][2], bv0[2][2], bv1[2][2];

#define RD_A(DST, BASE, OFF)                                   \
  _Pragma("unroll") for (int f = 0; f < 4; ++f) {              \
    DST[f][0] = *(const short8*)((BASE) + (OFF) + f * 2048 + sw0); \
    DST[f][1] = *(const short8*)((BASE) + (OFF) + f * 2048 + sw1); \
  }
#define RD_B(DST, BASE, OFF)                                   \
  _Pragma("unroll") for (int j = 0; j < 2; ++j) {              \
    DST[j][0] = *(const short8*)((BASE) + (OFF) + j * 2048 + sw0); \
    DST[j][1] = *(const short8*)((BASE) + (OFF) + j * 2048 + sw1); \
  }
#define MFMA16(FB, JB, AV, BV)                                                          \
  __builtin_amdgcn_s_setprio(1);                                                        \
  _Pragma("unroll") for (int f = 0; f < 4; ++f) _Pragma("unroll") for (int j = 0; j < 2; ++j) { \
    f32x4 c = acc[FB + f][JB + j];                                                      \
    c = __builtin_amdgcn_mfma_f32_16x16x32_bf16(AV[f][0], BV[j][0], c, 0, 0, 0);        \
    c = __builtin_amdgcn_mfma_f32_16x16x32_bf16(AV[f][1], BV[j][1], c, 0, 0, 0);        \
    acc[FB + f][JB + j] = c;                                                            \
  }                                                                                     \
  __builtin_amdgcn_s_setprio(0)

  // TILE body: BUF compile-time (0/1). Reads: ph0 bv0+bv1(T); ph1 av1(T); ph3 av0(T+1).
#define TILE(BUF, TT)                                                   \
  {                                                                     \
    const char* ab = (BUF) ? aR1 : aR0;                                 \
    const char* bb = (BUF) ? bR1 : bR0;                                 \
    const char* abn = (BUF) ? aR0 : aR1;                                \
    const int ob = (BUF) ^ 1;                                           \
    const int kn = ((TT) + 1) & 63;                                     \
    /* ph0 */                                                           \
    RD_B(bv0, bb, 0);                                                   \
    RD_B(bv1, bb, 4096);                                                \
    stA(ob, 0, kn);                                                     \
    MFMA16(0, 0, av0, bv0);                                             \
    VMC(2); PH_BAR();                                                   \
    /* ph1 */                                                           \
    RD_A(av1, ab, 8192);                                                \
    stB(ob, 0, kn); stB(ob, 1, kn);                                     \
    MFMA16(0, 2, av0, bv1);                                             \
    VMC(6); PH_BAR();                                                   \
    /* ph2 */                                                           \
    stA(ob, 1, kn);                                                     \
    MFMA16(4, 2, av1, bv1);                                             \
    VMC(6); PH_BAR();                                                   \
    /* ph3: lookahead av0(T+1) from other buffer */                     \
    RD_A(av0, abn, 0);                                                  \
    MFMA16(4, 0, av1, bv0);                                             \
    VMC(2); PH_BAR();                                                   \
  }

  // prologue: tile0 full (8 loads) + B0,B1(1) (4) + A1(1) (2); retire tile0; preload av0(0)
  stA(0, 0, 0); stB(0, 0, 0); stB(0, 1, 0); stA(0, 1, 0);
  stB(1, 0, 1); stB(1, 1, 1);
  stA(1, 1, 1);
  VMC(6);
  PH_BAR();
  RD_A(av0, aR0, 0);

  for (int u = 0; u < 32; ++u) {
    TILE(0, 2 * u);
    TILE(1, 2 * u + 1);
  }

  // epilogue: C layout col=lane&15, row=(lane>>4)*4+e
  const int orow = m0 + wm * 128 + hi * 4;
  const int ocol = n0 + wn * 64 + r15;
  float bb4[4];
#pragma unroll
  for (int j = 0; j < 4; ++j) bb4[j] = bias[ocol + j * 16];
#pragma unroll
  for (int i = 0; i < 8; ++i)
#pragma unroll
    for (int j = 0; j < 4; ++j)
#pragma unroll
      for (int e = 0; e < 4; ++e)
        out[(size_t)(orow + i * 16 + e) * TDIM + (ocol + j * 16)] = acc[i][j][e] + bb4[j];
}

extern "C" void kernel_launch(void* const* d_in, const int* in_sizes, int n_in,
                              void* d_out, int out_size, void* d_ws, size_t ws_size,
                              hipStream_t stream) {
  const float* x = (const float*)d_in[0];
  const unsigned* qw = (const unsigned*)d_in[1];
  const float* scales = (const float*)d_in[2];
  const float* zeros = (const float*)d_in[3];
  const float* bias = (const float*)d_in[4];
  float* out = (float*)d_out;

  unsigned short* wt = (unsigned short*)d_ws;
  unsigned short* xbf = (unsigned short*)((char*)d_ws + (size_t)TDIM * KDIM * 2);

  dequant_k<<<5504, 256, 0, stream>>>(qw, scales, zeros, wt);
  cvtx_k<<<8192, 256, 0, stream>>>(x, xbf);
  gemm5_k<<<688, 512, 0, stream>>>(xbf, wt, bias, out);
}

// Round 6
// 429.133 us; speedup vs baseline: 1.3557x; 1.3557x over previous
//
#include <hip/hip_runtime.h>
#include <hip/hip_bf16.h>
#include <stdint.h>

typedef short short8 __attribute__((ext_vector_type(8)));
typedef float f32x4 __attribute__((ext_vector_type(4)));
typedef float float4v __attribute__((ext_vector_type(4)));

#define KDIM 4096
#define TDIM 11008
#define BDIM 4096

static __device__ __forceinline__ unsigned short f2bf(float f) {
  unsigned u = __builtin_bit_cast(unsigned, f);
  u += 0x7FFFu + ((u >> 16) & 1u);
  return (unsigned short)(u >> 16);
}

// ---------------- kernel 1: dequant int4 -> bf16, transposed Wt[T][K] ----------------
__global__ __launch_bounds__(256) void dequant_k(const unsigned* __restrict__ qw,
                                                 const float* __restrict__ scales,
                                                 const float* __restrict__ zeros,
                                                 unsigned short* __restrict__ wt) {
  int idx = blockIdx.x * 256 + threadIdx.x;
  int rb = idx / TDIM;
  int t = idx - rb * TDIM;
  int r0 = rb * 4;
  int g = rb >> 2;
  float s = scales[(size_t)g * TDIM + t];
  float z = zeros[(size_t)g * TDIM + t];
  float nzs = -z * s;
#pragma unroll
  for (int c = 0; c < 4; ++c) {
    unsigned q = qw[(size_t)(r0 + c) * TDIM + t];
    short8 o;
#pragma unroll
    for (int i = 0; i < 8; ++i) {
      float w = fmaf((float)((q >> (4 * i)) & 0xFu), s, nzs);
      o[i] = (short)f2bf(w);
    }
    *(short8*)(wt + (size_t)t * KDIM + (r0 + c) * 8) = o;
  }
}

// ---------------- kernel 2: x f32 -> bf16 ----------------
__global__ __launch_bounds__(256) void cvtx_k(const float* __restrict__ x,
                                              unsigned short* __restrict__ xb) {
  size_t i = ((size_t)blockIdx.x * 256 + threadIdx.x) * 8;
  float4v a = *(const float4v*)(x + i);
  float4v b = *(const float4v*)(x + i + 4);
  short8 o;
  o[0] = (short)f2bf(a[0]); o[1] = (short)f2bf(a[1]);
  o[2] = (short)f2bf(a[2]); o[3] = (short)f2bf(a[3]);
  o[4] = (short)f2bf(b[0]); o[5] = (short)f2bf(b[1]);
  o[6] = (short)f2bf(b[2]); o[7] = (short)f2bf(b[3]);
  *(short8*)(xb + i) = o;
}

// ---------------- kernel 3: 256x256 bf16 GEMM, m201-faithful 4-phase/tile ----------
// Phase = { ds_reads (12/8/4/0), stage 1 half-set -> OTHER buffer, [lgkmcnt(8) if 12],
//           barrier, lgkmcnt(0), setprio(1), 16 MFMA, setprio(0), vmcnt(4), barrier }.
// vmcnt(4) only ever waits on loads staged >=3 phases ago (landed long ago); in-flight
// never drops below 4; no vmcnt(0) anywhere. Stage targets the other buffer whose
// region's last ds_read was >=4 barriers earlier -> WAR race-free by construction.
static __device__ __forceinline__ void gload16(const void* g, void* l) {
  __builtin_amdgcn_global_load_lds(
      (const __attribute__((address_space(1))) unsigned*)g,
      (__attribute__((address_space(3))) unsigned*)l, 16, 0, 0);
}

#define BARR() __builtin_amdgcn_s_barrier()
#define LGKM0() asm volatile("s_waitcnt lgkmcnt(0)" ::: "memory")
#define LGKM8() asm volatile("s_waitcnt lgkmcnt(8)" ::: "memory")
#define VMC4() asm volatile("s_waitcnt vmcnt(4)" ::: "memory")

__global__ __launch_bounds__(512, 2) void gemm6_k(const unsigned short* __restrict__ xb,
                                                  const unsigned short* __restrict__ wt,
                                                  const float* __restrict__ bias,
                                                  float* __restrict__ out) {
  __shared__ unsigned short sA[2 * 256 * 64];  // 64 KiB [buf][row][64K], 128B rows, XOR swz
  __shared__ unsigned short sB[2 * 256 * 64];  // 64 KiB
  const int tid = threadIdx.x;
  const int lane = tid & 63;
  const int wid = tid >> 6;
  const int wm = wid >> 2, wn = wid & 3;

  // XCD swizzle: nwg = 16*43 = 688 = 8*86
  const int bid = blockIdx.x;
  const int swz = (bid & 7) * 86 + (bid >> 3);
  const int mb = swz / 43, nb = swz % 43;
  const int m0 = mb * 256, n0 = nb * 256;

  char* sAc = (char*)sA;
  char* sBc = (char*)sB;

  // staging precompute (3-bit XOR both-sides swizzle, R4-verified conflict-free)
  const int sr = tid >> 3;
  const int pcb = (tid & 7) * 16;
  const int kbel = ((tid & 7) ^ (sr & 7)) * 8;
  const int grB = (sr >> 5) * 64 + (sr & 31);
  const unsigned short* srcA = xb + (size_t)m0 * KDIM + kbel;
  const unsigned short* srcB = wt + (size_t)n0 * KDIM + kbel;

  auto stage2 = [&](const unsigned short* src, char* dst, int gr, int koff) {
    gload16(src + (size_t)gr * KDIM + koff, dst + gr * 128);
    gload16(src + (size_t)(gr + 128) * KDIM + koff, dst + (gr + 128) * 128);
  };
  auto stA = [&](int b, int QM, int kt) { stage2(srcA, sAc + b * 32768 + pcb, QM * 64 + sr, kt * 64); };
  auto stB = [&](int b, int QN, int kt) { stage2(srcB, sBc + b * 32768 + pcb, QN * 32 + grB, kt * 64); };

  // read addressing: phys chunk = (ks*4+hi) ^ (r15&7)
  const int r15 = lane & 15;
  const int hi = lane >> 4;
  const int sw0 = ((hi) ^ (r15 & 7)) * 16;
  const int sw1 = ((4 + hi) ^ (r15 & 7)) * 16;
  const char* aR0 = sAc + (wm * 128 + r15) * 128;
  const char* aR1 = sAc + 32768 + (wm * 128 + r15) * 128;
  const char* bR0 = sBc + (wn * 64 + r15) * 128;
  const char* bR1 = sBc + 32768 + (wn * 64 + r15) * 128;

  f32x4 acc[8][4];
#pragma unroll
  for (int i = 0; i < 8; ++i)
#pragma unroll
    for (int j = 0; j < 4; ++j) acc[i][j] = (f32x4){0.f, 0.f, 0.f, 0.f};

  short8 av0[4][2], av1[4][2], bv0[2][2], bv1[2][2];

#define RD_A(DST, BASE, OFF)                                   \
  _Pragma("unroll") for (int f = 0; f < 4; ++f) {              \
    DST[f][0] = *(const short8*)((BASE) + (OFF) + f * 2048 + sw0); \
    DST[f][1] = *(const short8*)((BASE) + (OFF) + f * 2048 + sw1); \
  }
#define RD_B(DST, BASE, OFF)                                   \
  _Pragma("unroll") for (int j = 0; j < 2; ++j) {              \
    DST[j][0] = *(const short8*)((BASE) + (OFF) + j * 2048 + sw0); \
    DST[j][1] = *(const short8*)((BASE) + (OFF) + j * 2048 + sw1); \
  }
#define MFMA16(FB, JB, AV, BV)                                                          \
  __builtin_amdgcn_s_setprio(1);                                                        \
  _Pragma("unroll") for (int f = 0; f < 4; ++f) _Pragma("unroll") for (int j = 0; j < 2; ++j) { \
    f32x4 c = acc[FB + f][JB + j];                                                      \
    c = __builtin_amdgcn_mfma_f32_16x16x32_bf16(AV[f][0], BV[j][0], c, 0, 0, 0);        \
    c = __builtin_amdgcn_mfma_f32_16x16x32_bf16(AV[f][1], BV[j][1], c, 0, 0, 0);        \
    acc[FB + f][JB + j] = c;                                                            \
  }                                                                                     \
  __builtin_amdgcn_s_setprio(0)

  // Quadrant order Q00 -> Q10 -> Q11 -> Q01 (bv0 dies after P1; max frag-live 80 VGPR).
  // Stage order A0,B0,A1,B1 of tile T+1 (matches T+1's read order) -> other buffer.
#define TILE(BUF, TT)                                                   \
  {                                                                     \
    const char* ab = (BUF) ? aR1 : aR0;                                 \
    const char* bb = (BUF) ? bR1 : bR0;                                 \
    const int ob = (BUF) ^ 1;                                           \
    const int kn = ((TT) + 1) & 63;                                     \
    /* P0: Q00 (av0, bv0) ; 12 reads */                                 \
    RD_A(av0, ab, 0);                                                   \
    RD_B(bv0, bb, 0);                                                   \
    stA(ob, 0, kn);                                                     \
    LGKM8();                                                            \
    BARR(); LGKM0();                                                    \
    MFMA16(0, 0, av0, bv0);                                             \
    VMC4(); BARR();                                                     \
    /* P1: Q10 (av1, bv0) ; 8 reads */                                  \
    RD_A(av1, ab, 8192);                                                \
    stB(ob, 0, kn);                                                     \
    BARR(); LGKM0();                                                    \
    MFMA16(4, 0, av1, bv0);                                             \
    VMC4(); BARR();                                                     \
    /* P2: Q11 (av1, bv1) ; 4 reads */                                  \
    RD_B(bv1, bb, 4096);                                                \
    stA(ob, 1, kn);                                                     \
    BARR(); LGKM0();                                                    \
    MFMA16(4, 2, av1, bv1);                                             \
    VMC4(); BARR();                                                     \
    /* P3: Q01 (av0, bv1) ; 0 reads */                                  \
    stB(ob, 1, kn);                                                     \
    BARR(); LGKM0();                                                    \
    MFMA16(0, 2, av0, bv1);                                             \
    VMC4(); BARR();                                                     \
  }

  // prologue: tile0 fully staged; vmcnt(4) -> A0,B0 landed (A1,B1 may stay in flight)
  stA(0, 0, 0); stB(0, 0, 0);
  stA(0, 1, 0); stB(0, 1, 0);
  VMC4();
  BARR();

  for (int u = 0; u < 32; ++u) {
    TILE(0, 2 * u);
    TILE(1, 2 * u + 1);
  }

  // epilogue: C layout col=lane&15, row=(lane>>4)*4+e
  const int orow = m0 + wm * 128 + hi * 4;
  const int ocol = n0 + wn * 64 + r15;
  float bb4[4];
#pragma unroll
  for (int j = 0; j < 4; ++j) bb4[j] = bias[ocol + j * 16];
#pragma unroll
  for (int i = 0; i < 8; ++i)
#pragma unroll
    for (int j = 0; j < 4; ++j)
#pragma unroll
      for (int e = 0; e < 4; ++e)
        out[(size_t)(orow + i * 16 + e) * TDIM + (ocol + j * 16)] = acc[i][j][e] + bb4[j];
}

extern "C" void kernel_launch(void* const* d_in, const int* in_sizes, int n_in,
                              void* d_out, int out_size, void* d_ws, size_t ws_size,
                              hipStream_t stream) {
  const float* x = (const float*)d_in[0];
  const unsigned* qw = (const unsigned*)d_in[1];
  const float* scales = (const float*)d_in[2];
  const float* zeros = (const float*)d_in[3];
  const float* bias = (const float*)d_in[4];
  float* out = (float*)d_out;

  unsigned short* wt = (unsigned short*)d_ws;
  unsigned short* xbf = (unsigned short*)((char*)d_ws + (size_t)TDIM * KDIM * 2);

  dequant_k<<<5504, 256, 0, stream>>>(qw, scales, zeros, wt);
  cvtx_k<<<8192, 256, 0, stream>>>(x, xbf);
  gemm6_k<<<688, 512, 0, stream>>>(xbf, wt, bias, out);
}

// Round 7
// 426.872 us; speedup vs baseline: 1.3629x; 1.0053x over previous
//
#include <hip/hip_runtime.h>
#include <hip/hip_bf16.h>
#include <stdint.h>

typedef short short8 __attribute__((ext_vector_type(8)));
typedef float f32x4 __attribute__((ext_vector_type(4)));
typedef float float4v __attribute__((ext_vector_type(4)));

#define KDIM 4096
#define TDIM 11008
#define BDIM 4096

static __device__ __forceinline__ unsigned short f2bf(float f) {
  unsigned u = __builtin_bit_cast(unsigned, f);
  u += 0x7FFFu + ((u >> 16) & 1u);
  return (unsigned short)(u >> 16);
}

// ---------------- kernel 1: dequant int4 -> bf16, transposed Wt[T][K] ----------------
__global__ __launch_bounds__(256) void dequant_k(const unsigned* __restrict__ qw,
                                                 const float* __restrict__ scales,
                                                 const float* __restrict__ zeros,
                                                 unsigned short* __restrict__ wt) {
  int idx = blockIdx.x * 256 + threadIdx.x;
  int rb = idx / TDIM;
  int t = idx - rb * TDIM;
  int r0 = rb * 4;
  int g = rb >> 2;
  float s = scales[(size_t)g * TDIM + t];
  float z = zeros[(size_t)g * TDIM + t];
  float nzs = -z * s;
#pragma unroll
  for (int c = 0; c < 4; ++c) {
    unsigned q = qw[(size_t)(r0 + c) * TDIM + t];
    short8 o;
#pragma unroll
    for (int i = 0; i < 8; ++i) {
      float w = fmaf((float)((q >> (4 * i)) & 0xFu), s, nzs);
      o[i] = (short)f2bf(w);
    }
    *(short8*)(wt + (size_t)t * KDIM + (r0 + c) * 8) = o;
  }
}

// ---------------- kernel 2: x f32 -> bf16 ----------------
__global__ __launch_bounds__(256) void cvtx_k(const float* __restrict__ x,
                                              unsigned short* __restrict__ xb) {
  size_t i = ((size_t)blockIdx.x * 256 + threadIdx.x) * 8;
  float4v a = *(const float4v*)(x + i);
  float4v b = *(const float4v*)(x + i + 4);
  short8 o;
  o[0] = (short)f2bf(a[0]); o[1] = (short)f2bf(a[1]);
  o[2] = (short)f2bf(a[2]); o[3] = (short)f2bf(a[3]);
  o[4] = (short)f2bf(b[0]); o[5] = (short)f2bf(b[1]);
  o[6] = (short)f2bf(b[2]); o[7] = (short)f2bf(b[3]);
  *(short8*)(xb + i) = o;
}

// ---------------- kernel 3: 256x256 bf16 GEMM, m201-exact counted-vmcnt pipeline ----
// Per TILE(BUF,T), 4 phases: reads 12/8/4/0, one stage per phase, ONE vmcnt(6) at P3.
// Stage slots: P0: B1(T+1)->BUF^1 ; P1: A0(T+2)->BUF ; P2: B0(T+2)->BUF ; P3: A1(T+2)->BUF.
// Invariant: entering a tile, 6 loads outstanding = {A0,B0,A1}(T+1); its vmcnt(6)
// retires carry-in + P0 => T+1 fully published one barrier before its first read.
// WAR: every stage hits a region whose last ds_read drained >=1 barrier earlier.
static __device__ __forceinline__ void gload16(const void* g, void* l) {
  __builtin_amdgcn_global_load_lds(
      (const __attribute__((address_space(1))) unsigned*)g,
      (__attribute__((address_space(3))) unsigned*)l, 16, 0, 0);
}

#define BARR() __builtin_amdgcn_s_barrier()
#define LGKM0() asm volatile("s_waitcnt lgkmcnt(0)" ::: "memory")
#define LGKM8() asm volatile("s_waitcnt lgkmcnt(8)" ::: "memory")
#define VMC6() asm volatile("s_waitcnt vmcnt(6)" ::: "memory")

__global__ __launch_bounds__(512, 2) void gemm7_k(const unsigned short* __restrict__ xb,
                                                  const unsigned short* __restrict__ wt,
                                                  const float* __restrict__ bias,
                                                  float* __restrict__ out) {
  __shared__ unsigned short sA[2 * 256 * 64];  // 64 KiB [buf][row][64K], 128B rows, XOR swz
  __shared__ unsigned short sB[2 * 256 * 64];  // 64 KiB
  const int tid = threadIdx.x;
  const int lane = tid & 63;
  const int wid = tid >> 6;
  const int wm = wid >> 2, wn = wid & 3;

  // XCD swizzle: nwg = 16*43 = 688 = 8*86
  const int bid = blockIdx.x;
  const int swz = (bid & 7) * 86 + (bid >> 3);
  const int mb = swz / 43, nb = swz % 43;
  const int m0 = mb * 256, n0 = nb * 256;

  char* sAc = (char*)sA;
  char* sBc = (char*)sB;

  // staging precompute (3-bit XOR both-sides swizzle, R4/R6-verified conflict-free)
  const int sr = tid >> 3;
  const int pcb = (tid & 7) * 16;
  const int kbel = ((tid & 7) ^ (sr & 7)) * 8;
  const int grB = (sr >> 5) * 64 + (sr & 31);
  const unsigned short* srcA = xb + (size_t)m0 * KDIM + kbel;
  const unsigned short* srcB = wt + (size_t)n0 * KDIM + kbel;

  auto stage2 = [&](const unsigned short* src, char* dst, int gr, int koff) {
    gload16(src + (size_t)gr * KDIM + koff, dst + gr * 128);
    gload16(src + (size_t)(gr + 128) * KDIM + koff, dst + (gr + 128) * 128);
  };
  auto stA = [&](int b, int QM, int kt) { stage2(srcA, sAc + b * 32768 + pcb, QM * 64 + sr, kt * 64); };
  auto stB = [&](int b, int QN, int kt) { stage2(srcB, sBc + b * 32768 + pcb, QN * 32 + grB, kt * 64); };

  // read addressing: phys chunk = (ks*4+hi) ^ (r15&7)
  const int r15 = lane & 15;
  const int hi = lane >> 4;
  const int sw0 = ((hi) ^ (r15 & 7)) * 16;
  const int sw1 = ((4 + hi) ^ (r15 & 7)) * 16;
  const char* aR0 = sAc + (wm * 128 + r15) * 128;
  const char* aR1 = sAc + 32768 + (wm * 128 + r15) * 128;
  const char* bR0 = sBc + (wn * 64 + r15) * 128;
  const char* bR1 = sBc + 32768 + (wn * 64 + r15) * 128;

  f32x4 acc[8][4];
#pragma unroll
  for (int i = 0; i < 8; ++i)
#pragma unroll
    for (int j = 0; j < 4; ++j) acc[i][j] = (f32x4){0.f, 0.f, 0.f, 0.f};

  short8 av0[4][2], av1[4][2], bv0[2][2], bv1[2][2];

#define RD_A(DST, BASE, OFF)                                   \
  _Pragma("unroll") for (int f = 0; f < 4; ++f) {              \
    DST[f][0] = *(const short8*)((BASE) + (OFF) + f * 2048 + sw0); \
    DST[f][1] = *(const short8*)((BASE) + (OFF) + f * 2048 + sw1); \
  }
#define RD_B(DST, BASE, OFF)                                   \
  _Pragma("unroll") for (int j = 0; j < 2; ++j) {              \
    DST[j][0] = *(const short8*)((BASE) + (OFF) + j * 2048 + sw0); \
    DST[j][1] = *(const short8*)((BASE) + (OFF) + j * 2048 + sw1); \
  }
#define MFMA16(FB, JB, AV, BV)                                                          \
  __builtin_amdgcn_s_setprio(1);                                                        \
  _Pragma("unroll") for (int f = 0; f < 4; ++f) _Pragma("unroll") for (int j = 0; j < 2; ++j) { \
    f32x4 c = acc[FB + f][JB + j];                                                      \
    c = __builtin_amdgcn_mfma_f32_16x16x32_bf16(AV[f][0], BV[j][0], c, 0, 0, 0);        \
    c = __builtin_amdgcn_mfma_f32_16x16x32_bf16(AV[f][1], BV[j][1], c, 0, 0, 0);        \
    acc[FB + f][JB + j] = c;                                                            \
  }                                                                                     \
  __builtin_amdgcn_s_setprio(0)

  // Quadrant order Q00 -> Q10 -> Q11 -> Q01.
#define TILE(BUF, TT)                                                   \
  {                                                                     \
    const char* ab = (BUF) ? aR1 : aR0;                                 \
    const char* bb = (BUF) ? bR1 : bR0;                                 \
    const int ob = (BUF) ^ 1;                                           \
    const int k1 = ((TT) + 1) & 63;                                     \
    const int k2 = ((TT) + 2) & 63;                                     \
    /* P0: Q00 (av0, bv0); 12 reads; stage B1(T+1)->other buf */        \
    RD_A(av0, ab, 0);                                                   \
    RD_B(bv0, bb, 0);                                                   \
    stB(ob, 1, k1);                                                     \
    LGKM8();                                                            \
    BARR(); LGKM0();                                                    \
    MFMA16(0, 0, av0, bv0);                                             \
    BARR();                                                             \
    /* P1: Q10 (av1, bv0); 8 reads; stage A0(T+2)->this buf */          \
    RD_A(av1, ab, 8192);                                                \
    stA(BUF, 0, k2);                                                    \
    BARR(); LGKM0();                                                    \
    MFMA16(4, 0, av1, bv0);                                             \
    BARR();                                                             \
    /* P2: Q11 (av1, bv1); 4 reads; stage B0(T+2)->this buf */          \
    RD_B(bv1, bb, 4096);                                                \
    stB(BUF, 0, k2);                                                    \
    BARR(); LGKM0();                                                    \
    MFMA16(4, 2, av1, bv1);                                             \
    BARR();                                                             \
    /* P3: Q01 (av0, bv1); 0 reads; stage A1(T+2)->this buf; ONE vmcnt */ \
    stA(BUF, 1, k2);                                                    \
    BARR();                                                             \
    MFMA16(0, 2, av0, bv1);                                             \
    VMC6(); BARR();                                                     \
  }

  // prologue: tile0 full (8 loads) then A0,B0,A1 of tile1 (6 loads);
  // vmcnt(6) retires exactly tile0; carry-in = {A0,B0,A1}(1) matches invariant.
  stA(0, 0, 0); stB(0, 0, 0); stA(0, 1, 0); stB(0, 1, 0);
  stA(1, 0, 1); stB(1, 0, 1); stA(1, 1, 1);
  VMC6();
  BARR();

  for (int u = 0; u < 32; ++u) {
    TILE(0, 2 * u);
    TILE(1, 2 * u + 1);
  }

  // epilogue: C layout col=lane&15, row=(lane>>4)*4+e
  const int orow = m0 + wm * 128 + hi * 4;
  const int ocol = n0 + wn * 64 + r15;
  float bb4[4];
#pragma unroll
  for (int j = 0; j < 4; ++j) bb4[j] = bias[ocol + j * 16];
#pragma unroll
  for (int i = 0; i < 8; ++i)
#pragma unroll
    for (int j = 0; j < 4; ++j)
#pragma unroll
      for (int e = 0; e < 4; ++e)
        out[(size_t)(orow + i * 16 + e) * TDIM + (ocol + j * 16)] = acc[i][j][e] + bb4[j];
}

extern "C" void kernel_launch(void* const* d_in, const int* in_sizes, int n_in,
                              void* d_out, int out_size, void* d_ws, size_t ws_size,
                              hipStream_t stream) {
  const float* x = (const float*)d_in[0];
  const unsigned* qw = (const unsigned*)d_in[1];
  const float* scales = (const float*)d_in[2];
  const float* zeros = (const float*)d_in[3];
  const float* bias = (const float*)d_in[4];
  float* out = (float*)d_out;

  unsigned short* wt = (unsigned short*)d_ws;
  unsigned short* xbf = (unsigned short*)((char*)d_ws + (size_t)TDIM * KDIM * 2);

  dequant_k<<<5504, 256, 0, stream>>>(qw, scales, zeros, wt);
  cvtx_k<<<8192, 256, 0, stream>>>(x, xbf);
  gemm7_k<<<688, 512, 0, stream>>>(xbf, wt, bias, out);
}

// Round 8
// 295.547 us; speedup vs baseline: 1.9685x; 1.4443x over previous
//
#include <hip/hip_runtime.h>
#include <hip/hip_bf16.h>
#include <stdint.h>

typedef int int4v __attribute__((ext_vector_type(4)));
typedef int int16v __attribute__((ext_vector_type(16)));
typedef float float4v __attribute__((ext_vector_type(4)));

#define KDIM 4096
#define TDIM 11008
#define BDIM 4096
#define GDIM 32

// ---------- kernel 0: per-column weight scale  dwt[t] = max_g s*max(z,15-z) / 127 ----------
__global__ __launch_bounds__(256) void dwt_k(const float* __restrict__ scales,
                                             const float* __restrict__ zeros,
                                             float* __restrict__ dwt,
                                             float* __restrict__ dwtinv) {
  int t = blockIdx.x * 256 + threadIdx.x;  // 43*256 = 11008 exact
  float m = 1e-20f;
#pragma unroll 4
  for (int g = 0; g < GDIM; ++g) {
    float s = scales[(size_t)g * TDIM + t];
    float z = zeros[(size_t)g * TDIM + t];
    m = fmaxf(m, s * fmaxf(z, 15.0f - z));
  }
  dwt[t] = m * (1.0f / 127.0f);
  dwtinv[t] = 127.0f / m;
}

// ---------- kernel 1: dequant int4 -> int8, transposed wq[T][K] ----------
__global__ __launch_bounds__(256) void dequantq_k(const unsigned* __restrict__ qw,
                                                  const float* __restrict__ scales,
                                                  const float* __restrict__ zeros,
                                                  const float* __restrict__ dwtinv,
                                                  char* __restrict__ wq) {
  int idx = blockIdx.x * 256 + threadIdx.x;  // 128*TDIM exact
  int rb = idx / TDIM;
  int t = idx - rb * TDIM;
  int r0 = rb * 4, g = rb >> 2;
  float s = scales[(size_t)g * TDIM + t];
  float z = zeros[(size_t)g * TDIM + t];
  float inv = dwtinv[t];
  float si = s * inv;
  float zi = -z * si;
  int w[8];
#pragma unroll
  for (int c = 0; c < 4; ++c) {
    unsigned q = qw[(size_t)(r0 + c) * TDIM + t];
    unsigned lo = 0, hi = 0;
#pragma unroll
    for (int i = 0; i < 4; ++i) {
      int iv = (int)rintf(fmaf((float)((q >> (4 * i)) & 0xFu), si, zi));
      lo |= (unsigned)(iv & 0xFF) << (8 * i);
    }
#pragma unroll
    for (int i = 4; i < 8; ++i) {
      int iv = (int)rintf(fmaf((float)((q >> (4 * i)) & 0xFu), si, zi));
      hi |= (unsigned)(iv & 0xFF) << (8 * (i - 4));
    }
    w[2 * c] = (int)lo;
    w[2 * c + 1] = (int)hi;
  }
  int4v v0 = {w[0], w[1], w[2], w[3]};
  int4v v1 = {w[4], w[5], w[6], w[7]};
  char* dst = wq + (size_t)t * KDIM + rb * 32;
  *(int4v*)dst = v0;
  *(int4v*)(dst + 16) = v1;
}

// ---------- kernel 2: per-row x max + quantize to int8 ----------
__global__ __launch_bounds__(256) void xq_k(const float* __restrict__ x,
                                            char* __restrict__ xq,
                                            float* __restrict__ dxr) {
  const int b = blockIdx.x;
  const int tid = threadIdx.x;
  const float* row = x + (size_t)b * KDIM;
  float4v v[4];
  float m = 0.0f;
#pragma unroll
  for (int j = 0; j < 4; ++j) {
    v[j] = *(const float4v*)(row + (tid + 256 * j) * 4);
#pragma unroll
    for (int i = 0; i < 4; ++i) m = fmaxf(m, fabsf(v[j][i]));
  }
#pragma unroll
  for (int off = 1; off < 64; off <<= 1) m = fmaxf(m, __shfl_xor(m, off));
  __shared__ float sm[4];
  if ((tid & 63) == 0) sm[tid >> 6] = m;
  __syncthreads();
  float rm = fmaxf(fmaxf(sm[0], sm[1]), fmaxf(sm[2], sm[3]));
  rm = fmaxf(rm, 1e-20f);
  if (tid == 0) dxr[b] = rm * (1.0f / 127.0f);
  float inv = 127.0f / rm;
#pragma unroll
  for (int j = 0; j < 4; ++j) {
    unsigned w = 0;
#pragma unroll
    for (int i = 0; i < 4; ++i) {
      int iv = (int)rintf(v[j][i] * inv);
      w |= (unsigned)(iv & 0xFF) << (8 * i);
    }
    *(unsigned*)(xq + (size_t)b * KDIM + (tid + 256 * j) * 4) = w;
  }
}

// ---------- kernel 3: 256x256 i8 GEMM, 1 phase/tile, 32x32x32_i8 ----------
// Phase: {12 ds_read_b128; lgkm pace; barrier; lgkmcnt(0); stage A+B(T+2)->same buf
// (post-read, R3-validated write window); 16 MFMA; vmcnt(4); barrier}. vmcnt never
// drains below 4. LDS 64KB total. Swizzle: phys chunk = logical ^ (row&3) ^ ((row>>2)&3)
// (8 accesses/bank = wave64 minimum on read; staging dest linear per wave).
static __device__ __forceinline__ void gload16(const void* g, void* l) {
  __builtin_amdgcn_global_load_lds(
      (const __attribute__((address_space(1))) unsigned*)g,
      (__attribute__((address_space(3))) unsigned*)l, 16, 0, 0);
}

#define BARR() __builtin_amdgcn_s_barrier()
#define LGKM0() asm volatile("s_waitcnt lgkmcnt(0)" ::: "memory")
#define LGKM8() asm volatile("s_waitcnt lgkmcnt(8)" ::: "memory")
#define VMC4() asm volatile("s_waitcnt vmcnt(4)" ::: "memory")
#define SB0() __builtin_amdgcn_sched_barrier(0)

__global__ __launch_bounds__(512, 2) void gemmq_k(const char* __restrict__ xq,
                                                  const char* __restrict__ wq,
                                                  const float* __restrict__ dxr,
                                                  const float* __restrict__ dwt,
                                                  const float* __restrict__ bias,
                                                  float* __restrict__ out) {
  __shared__ char sA[2 * 256 * 64];  // 32 KiB: [buf][row][64K] i8, 64B rows
  __shared__ char sB[2 * 256 * 64];  // 32 KiB
  const int tid = threadIdx.x;
  const int lane = tid & 63;
  const int wid = tid >> 6;
  const int wm = wid >> 2, wn = wid & 3;  // 2M x 4N waves; wave out 128x64

  // XCD swizzle: nwg = 16*43 = 688 = 8*86
  const int bid = blockIdx.x;
  const int swzb = (bid & 7) * 86 + (bid >> 3);
  const int mb = swzb / 43, nb = swzb % 43;
  const int m0 = mb * 256, n0 = nb * 256;

  // staging: chunk ci in {tid, tid+512}; row = ci>>2 (r, r+128), pc = tid&3
  const int srow = tid >> 2;  // 0..127
  const int spc = tid & 3;
  const int skb = spc ^ (srow & 3) ^ ((srow >> 2) & 3);
  const char* gA = xq + (size_t)(m0 + srow) * KDIM + skb * 16;
  const char* gB = wq + (size_t)(n0 + srow) * KDIM + skb * 16;
  const int d0 = tid * 16, d1 = tid * 16 + 8192;

  auto stA = [&](int b, int kt) {
    gload16(gA + kt * 64, sA + b * 16384 + d0);
    gload16(gA + (size_t)128 * KDIM + kt * 64, sA + b * 16384 + d1);
  };
  auto stB = [&](int b, int kt) {
    gload16(gB + kt * 64, sB + b * 16384 + d0);
    gload16(gB + (size_t)128 * KDIM + kt * 64, sB + b * 16384 + d1);
  };

  // read addressing
  const int l31 = lane & 31, hi5 = lane >> 5;
  const int swz = (l31 & 3) ^ ((l31 >> 2) & 3);
  const int pc0 = ((hi5 ^ swz)) * 16;        // ks=0
  const int pc1 = ((hi5 ^ swz) ^ 2) * 16;    // ks=1
  const char* aRd = sA + (wm * 128 + l31) * 64;
  const char* bRd = sB + (wn * 64 + l31) * 64;

  int16v acc[4][2];
#pragma unroll
  for (int i = 0; i < 4; ++i)
#pragma unroll
    for (int j = 0; j < 2; ++j) acc[i][j] = (int16v)(0);

#define TILEQ(BUF, TT)                                                        \
  {                                                                           \
    const char* ap = aRd + (BUF) * 16384;                                     \
    const char* bp = bRd + (BUF) * 16384;                                     \
    int4v av[4][2], bv[2][2];                                                 \
    _Pragma("unroll") for (int fi = 0; fi < 4; ++fi) {                        \
      av[fi][0] = *(const int4v*)(ap + fi * 2048 + pc0);                      \
      av[fi][1] = *(const int4v*)(ap + fi * 2048 + pc1);                      \
    }                                                                         \
    _Pragma("unroll") for (int fj = 0; fj < 2; ++fj) {                        \
      bv[fj][0] = *(const int4v*)(bp + fj * 2048 + pc0);                      \
      bv[fj][1] = *(const int4v*)(bp + fj * 2048 + pc1);                      \
    }                                                                         \
    LGKM8();                                                                  \
    BARR(); LGKM0(); SB0();                                                   \
    const int kn = ((TT) + 2) & 63;                                           \
    stA(BUF, kn); stB(BUF, kn);                                               \
    SB0();                                                                    \
    __builtin_amdgcn_s_setprio(1);                                            \
    _Pragma("unroll") for (int fi = 0; fi < 4; ++fi)                          \
      _Pragma("unroll") for (int fj = 0; fj < 2; ++fj) {                      \
        int16v c = acc[fi][fj];                                               \
        c = __builtin_amdgcn_mfma_i32_32x32x32_i8(av[fi][0], bv[fj][0], c, 0, 0, 0); \
        c = __builtin_amdgcn_mfma_i32_32x32x32_i8(av[fi][1], bv[fj][1], c, 0, 0, 0); \
        acc[fi][fj] = c;                                                      \
      }                                                                       \
    __builtin_amdgcn_s_setprio(0);                                            \
    VMC4(); BARR();                                                           \
  }

  // prologue: stage tiles 0,1 (8 loads); vmcnt(4) -> tile0 landed
  stA(0, 0); stB(0, 0);
  stA(1, 1); stB(1, 1);
  VMC4();
  BARR();

  for (int u = 0; u < 32; ++u) {
    TILEQ(0, 2 * u);
    TILEQ(1, 2 * u + 1);
  }

  // epilogue: C layout (32x32): col = lane&31, row = (e&3) + 8*(e>>2) + 4*(lane>>5)
  const int colb = n0 + wn * 64 + l31;
  const int rowb = m0 + wm * 128 + 4 * hi5;
#pragma unroll
  for (int fi = 0; fi < 4; ++fi) {
#pragma unroll
    for (int fj = 0; fj < 2; ++fj) {
      const int col = colb + fj * 32;
      const float dw = dwt[col];
      const float bs = bias[col];
      int16v c = acc[fi][fj];
#pragma unroll
      for (int e = 0; e < 16; ++e) {
        const int row = rowb + fi * 32 + (e & 3) + 8 * (e >> 2);
        out[(size_t)row * TDIM + col] = (float)c[e] * dw * dxr[row] + bs;
      }
    }
  }
}

extern "C" void kernel_launch(void* const* d_in, const int* in_sizes, int n_in,
                              void* d_out, int out_size, void* d_ws, size_t ws_size,
                              hipStream_t stream) {
  const float* x = (const float*)d_in[0];
  const unsigned* qw = (const unsigned*)d_in[1];
  const float* scales = (const float*)d_in[2];
  const float* zeros = (const float*)d_in[3];
  const float* bias = (const float*)d_in[4];
  float* out = (float*)d_out;

  char* ws = (char*)d_ws;
  char* wq = ws;                                   // [TDIM][KDIM] i8, 45.1MB
  char* xq = ws + (size_t)TDIM * KDIM;             // [BDIM][KDIM] i8, 16.8MB
  float* dwt = (float*)(ws + (size_t)TDIM * KDIM + (size_t)BDIM * KDIM);
  float* dwtinv = dwt + TDIM;
  float* dxr = dwtinv + TDIM;

  dwt_k<<<43, 256, 0, stream>>>(scales, zeros, dwt, dwtinv);
  dequantq_k<<<5504, 256, 0, stream>>>(qw, scales, zeros, dwtinv, wq);
  xq_k<<<4096, 256, 0, stream>>>(x, xq, dxr);
  gemmq_k<<<688, 512, 0, stream>>>(xq, wq, dxr, dwt, bias, out);
}

// Round 9
// 285.262 us; speedup vs baseline: 2.0394x; 1.0361x over previous
//
#include <hip/hip_runtime.h>
#include <hip/hip_bf16.h>
#include <stdint.h>

typedef int int4v __attribute__((ext_vector_type(4)));
typedef int int16v __attribute__((ext_vector_type(16)));
typedef float float4v __attribute__((ext_vector_type(4)));

#define KDIM 4096
#define TDIM 11008
#define BDIM 4096
#define GDIM 32

// ---------- kernel 0: per-column weight scale  dwt[t] = max_g s*max(z,15-z) / 127 ----------
__global__ __launch_bounds__(256) void dwt_k(const float* __restrict__ scales,
                                             const float* __restrict__ zeros,
                                             float* __restrict__ dwt,
                                             float* __restrict__ dwtinv) {
  int t = blockIdx.x * 256 + threadIdx.x;  // 43*256 = 11008 exact
  float m = 1e-20f;
#pragma unroll 4
  for (int g = 0; g < GDIM; ++g) {
    float s = scales[(size_t)g * TDIM + t];
    float z = zeros[(size_t)g * TDIM + t];
    m = fmaxf(m, s * fmaxf(z, 15.0f - z));
  }
  dwt[t] = m * (1.0f / 127.0f);
  dwtinv[t] = 127.0f / m;
}

// ---------- kernel 1: dequant int4 -> int8, transposed wq[T][K] ----------
__global__ __launch_bounds__(256) void dequantq_k(const unsigned* __restrict__ qw,
                                                  const float* __restrict__ scales,
                                                  const float* __restrict__ zeros,
                                                  const float* __restrict__ dwtinv,
                                                  char* __restrict__ wq) {
  int idx = blockIdx.x * 256 + threadIdx.x;  // 128*TDIM exact
  int rb = idx / TDIM;
  int t = idx - rb * TDIM;
  int r0 = rb * 4, g = rb >> 2;
  float s = scales[(size_t)g * TDIM + t];
  float z = zeros[(size_t)g * TDIM + t];
  float inv = dwtinv[t];
  float si = s * inv;
  float zi = -z * si;
  int w[8];
#pragma unroll
  for (int c = 0; c < 4; ++c) {
    unsigned q = qw[(size_t)(r0 + c) * TDIM + t];
    unsigned lo = 0, hi = 0;
#pragma unroll
    for (int i = 0; i < 4; ++i) {
      int iv = (int)rintf(fmaf((float)((q >> (4 * i)) & 0xFu), si, zi));
      lo |= (unsigned)(iv & 0xFF) << (8 * i);
    }
#pragma unroll
    for (int i = 4; i < 8; ++i) {
      int iv = (int)rintf(fmaf((float)((q >> (4 * i)) & 0xFu), si, zi));
      hi |= (unsigned)(iv & 0xFF) << (8 * (i - 4));
    }
    w[2 * c] = (int)lo;
    w[2 * c + 1] = (int)hi;
  }
  int4v v0 = {w[0], w[1], w[2], w[3]};
  int4v v1 = {w[4], w[5], w[6], w[7]};
  char* dst = wq + (size_t)t * KDIM + rb * 32;
  *(int4v*)dst = v0;
  *(int4v*)(dst + 16) = v1;
}

// ---------- kernel 2: per-row x max + quantize to int8 ----------
__global__ __launch_bounds__(256) void xq_k(const float* __restrict__ x,
                                            char* __restrict__ xq,
                                            float* __restrict__ dxr) {
  const int b = blockIdx.x;
  const int tid = threadIdx.x;
  const float* row = x + (size_t)b * KDIM;
  float4v v[4];
  float m = 0.0f;
#pragma unroll
  for (int j = 0; j < 4; ++j) {
    v[j] = *(const float4v*)(row + (tid + 256 * j) * 4);
#pragma unroll
    for (int i = 0; i < 4; ++i) m = fmaxf(m, fabsf(v[j][i]));
  }
#pragma unroll
  for (int off = 1; off < 64; off <<= 1) m = fmaxf(m, __shfl_xor(m, off));
  __shared__ float sm[4];
  if ((tid & 63) == 0) sm[tid >> 6] = m;
  __syncthreads();
  float rm = fmaxf(fmaxf(sm[0], sm[1]), fmaxf(sm[2], sm[3]));
  rm = fmaxf(rm, 1e-20f);
  if (tid == 0) dxr[b] = rm * (1.0f / 127.0f);
  float inv = 127.0f / rm;
#pragma unroll
  for (int j = 0; j < 4; ++j) {
    unsigned w = 0;
#pragma unroll
    for (int i = 0; i < 4; ++i) {
      int iv = (int)rintf(v[j][i] * inv);
      w |= (unsigned)(iv & 0xFF) << (8 * i);
    }
    *(unsigned*)(xq + (size_t)b * KDIM + (tid + 256 * j) * 4) = w;
  }
}

// ---------- kernel 3: 256x256 i8 GEMM, split-lgkmcnt overlapped phase ----------
// Per tile: issue ks0 reads (6 b128) then ks1 reads (6); BARR; lgkmcnt(6) -> ks0
// MFMA cluster runs WHILE ks1 reads drain; lgkmcnt(0) -> stage (R8-validated write
// window) + ks1 cluster; vmcnt(4); BARR. DS completion is in-order, so lgkmcnt(6)
// == "first 6 (ks0) done". sched_barrier(0) after each counted wait (rule #18).
static __device__ __forceinline__ void gload16(const void* g, void* l) {
  __builtin_amdgcn_global_load_lds(
      (const __attribute__((address_space(1))) unsigned*)g,
      (__attribute__((address_space(3))) unsigned*)l, 16, 0, 0);
}

#define BARR() __builtin_amdgcn_s_barrier()
#define LGKM0() asm volatile("s_waitcnt lgkmcnt(0)" ::: "memory")
#define LGKM6() asm volatile("s_waitcnt lgkmcnt(6)" ::: "memory")
#define VMC4() asm volatile("s_waitcnt vmcnt(4)" ::: "memory")
#define SB0() __builtin_amdgcn_sched_barrier(0)

__global__ __launch_bounds__(512, 2) void gemmq_k(const char* __restrict__ xq,
                                                  const char* __restrict__ wq,
                                                  const float* __restrict__ dxr,
                                                  const float* __restrict__ dwt,
                                                  const float* __restrict__ bias,
                                                  float* __restrict__ out) {
  __shared__ char sA[2 * 256 * 64];  // 32 KiB: [buf][row][64K] i8, 64B rows
  __shared__ char sB[2 * 256 * 64];  // 32 KiB
  const int tid = threadIdx.x;
  const int lane = tid & 63;
  const int wid = tid >> 6;
  const int wm = wid >> 2, wn = wid & 3;  // 2M x 4N waves; wave out 128x64

  // XCD swizzle: nwg = 16*43 = 688 = 8*86
  const int bid = blockIdx.x;
  const int swzb = (bid & 7) * 86 + (bid >> 3);
  const int mb = swzb / 43, nb = swzb % 43;
  const int m0 = mb * 256, n0 = nb * 256;

  // staging: chunk ci in {tid, tid+512}; row = ci>>2 (r, r+128), pc = tid&3
  const int srow = tid >> 2;  // 0..127
  const int spc = tid & 3;
  const int skb = spc ^ (srow & 3) ^ ((srow >> 2) & 3);
  const char* gA = xq + (size_t)(m0 + srow) * KDIM + skb * 16;
  const char* gB = wq + (size_t)(n0 + srow) * KDIM + skb * 16;
  const int d0 = tid * 16, d1 = tid * 16 + 8192;

  auto stA = [&](int b, int kt) {
    gload16(gA + kt * 64, sA + b * 16384 + d0);
    gload16(gA + (size_t)128 * KDIM + kt * 64, sA + b * 16384 + d1);
  };
  auto stB = [&](int b, int kt) {
    gload16(gB + kt * 64, sB + b * 16384 + d0);
    gload16(gB + (size_t)128 * KDIM + kt * 64, sB + b * 16384 + d1);
  };

  // read addressing
  const int l31 = lane & 31, hi5 = lane >> 5;
  const int swz = (l31 & 3) ^ ((l31 >> 2) & 3);
  const int pc0 = ((hi5 ^ swz)) * 16;        // ks=0
  const int pc1 = ((hi5 ^ swz) ^ 2) * 16;    // ks=1
  const char* aRd = sA + (wm * 128 + l31) * 64;
  const char* bRd = sB + (wn * 64 + l31) * 64;

  int16v acc[4][2];
#pragma unroll
  for (int i = 0; i < 4; ++i)
#pragma unroll
    for (int j = 0; j < 2; ++j) acc[i][j] = (int16v)(0);

#define TILEQ(BUF, TT)                                                        \
  {                                                                           \
    const char* ap = aRd + (BUF) * 16384;                                     \
    const char* bp = bRd + (BUF) * 16384;                                     \
    int4v av[4][2], bv[2][2];                                                 \
    /* issue ks0 group first (6 reads), then ks1 (6): in-order completion */  \
    _Pragma("unroll") for (int fi = 0; fi < 4; ++fi)                          \
      av[fi][0] = *(const int4v*)(ap + fi * 2048 + pc0);                      \
    _Pragma("unroll") for (int fj = 0; fj < 2; ++fj)                          \
      bv[fj][0] = *(const int4v*)(bp + fj * 2048 + pc0);                      \
    _Pragma("unroll") for (int fi = 0; fi < 4; ++fi)                          \
      av[fi][1] = *(const int4v*)(ap + fi * 2048 + pc1);                      \
    _Pragma("unroll") for (int fj = 0; fj < 2; ++fj)                          \
      bv[fj][1] = *(const int4v*)(bp + fj * 2048 + pc1);                      \
    SB0();                                                                    \
    BARR();                                                                   \
    LGKM6(); SB0();                                                           \
    __builtin_amdgcn_s_setprio(1);                                            \
    _Pragma("unroll") for (int fi = 0; fi < 4; ++fi)                          \
      _Pragma("unroll") for (int fj = 0; fj < 2; ++fj)                        \
        acc[fi][fj] = __builtin_amdgcn_mfma_i32_32x32x32_i8(av[fi][0], bv[fj][0], acc[fi][fj], 0, 0, 0); \
    __builtin_amdgcn_s_setprio(0);                                            \
    LGKM0(); SB0();                                                           \
    const int kn = ((TT) + 2) & 63;                                           \
    stA(BUF, kn); stB(BUF, kn);                                               \
    SB0();                                                                    \
    __builtin_amdgcn_s_setprio(1);                                            \
    _Pragma("unroll") for (int fi = 0; fi < 4; ++fi)                          \
      _Pragma("unroll") for (int fj = 0; fj < 2; ++fj)                        \
        acc[fi][fj] = __builtin_amdgcn_mfma_i32_32x32x32_i8(av[fi][1], bv[fj][1], acc[fi][fj], 0, 0, 0); \
    __builtin_amdgcn_s_setprio(0);                                            \
    VMC4(); BARR();                                                           \
  }

  // prologue: stage tiles 0,1 (8 loads); vmcnt(4) -> tile0 landed
  stA(0, 0); stB(0, 0);
  stA(1, 1); stB(1, 1);
  VMC4();
  BARR();

  for (int u = 0; u < 32; ++u) {
    TILEQ(0, 2 * u);
    TILEQ(1, 2 * u + 1);
  }

  // epilogue: C layout (32x32): col = lane&31, row = (e&3) + 8*(e>>2) + 4*(lane>>5)
  const int colb = n0 + wn * 64 + l31;
  const int rowb = m0 + wm * 128 + 4 * hi5;
#pragma unroll
  for (int fi = 0; fi < 4; ++fi) {
#pragma unroll
    for (int fj = 0; fj < 2; ++fj) {
      const int col = colb + fj * 32;
      const float dw = dwt[col];
      const float bs = bias[col];
      int16v c = acc[fi][fj];
#pragma unroll
      for (int e = 0; e < 16; ++e) {
        const int row = rowb + fi * 32 + (e & 3) + 8 * (e >> 2);
        out[(size_t)row * TDIM + col] = (float)c[e] * dw * dxr[row] + bs;
      }
    }
  }
}

extern "C" void kernel_launch(void* const* d_in, const int* in_sizes, int n_in,
                              void* d_out, int out_size, void* d_ws, size_t ws_size,
                              hipStream_t stream) {
  const float* x = (const float*)d_in[0];
  const unsigned* qw = (const unsigned*)d_in[1];
  const float* scales = (const float*)d_in[2];
  const float* zeros = (const float*)d_in[3];
  const float* bias = (const float*)d_in[4];
  float* out = (float*)d_out;

  char* ws = (char*)d_ws;
  char* wq = ws;                                   // [TDIM][KDIM] i8, 45.1MB
  char* xq = ws + (size_t)TDIM * KDIM;             // [BDIM][KDIM] i8, 16.8MB
  float* dwt = (float*)(ws + (size_t)TDIM * KDIM + (size_t)BDIM * KDIM);
  float* dwtinv = dwt + TDIM;
  float* dxr = dwtinv + TDIM;

  dwt_k<<<43, 256, 0, stream>>>(scales, zeros, dwt, dwtinv);
  dequantq_k<<<5504, 256, 0, stream>>>(qw, scales, zeros, dwtinv, wq);
  xq_k<<<4096, 256, 0, stream>>>(x, xq, dxr);
  gemmq_k<<<688, 512, 0, stream>>>(xq, wq, dxr, dwt, bias, out);
}